// Round 10
// baseline (104.507 us; speedup 1.0000x reference)
//
#include <hip/hip_runtime.h>

#define Bsz 4
#define Nn  256
#define OBSD 40
#define ACTD 8
#define HEADS 8
#define DIMD 32
#define Td  256
#define R   4   // rows per block

#define FMA4(accr, s, wv) \
    (accr).x = fmaf((s), (wv).x, (accr).x); \
    (accr).y = fmaf((s), (wv).y, (accr).y); \
    (accr).z = fmaf((s), (wv).z, (accr).z); \
    (accr).w = fmaf((s), (wv).w, (accr).w)

// K1: emb = relu(relu(obs @ We1 + be1) @ We2 + be2), R=4 rows per block.
// grid = B*N/R = 256 blocks, 256 threads. Blocks 0/1 zero snh/shid, block 2 ctr.
__global__ __launch_bounds__(256, 1) void k_emb(
                      const float* __restrict__ x,
                      const float* __restrict__ We1, const float* __restrict__ be1,
                      const float* __restrict__ We2, const float* __restrict__ be2,
                      float* __restrict__ emb,
                      float* __restrict__ snh, float* __restrict__ shid,
                      unsigned* __restrict__ ctr) {
    int g = blockIdx.x;
    int t = threadIdx.x;
    int row0 = g * R;
    int b = row0 >> 8;
    int n0 = row0 & 255;
    if (g == 0)      { for (int i = t; i < Bsz * Td; i += 256) snh[i]  = 0.f; }
    else if (g == 1) { for (int i = t; i < Bsz * Td; i += 256) shid[i] = 0.f; }
    else if (g == 2) { if (t < Bsz) ctr[t] = 0u; }

    __shared__ float4 obs_t[OBSD];
    __shared__ float4 h1_t[Td];
    __shared__ float4 part[4][R][64];
    if (t < R * OBSD) {
        int r = t & (R - 1), k = t >> 2;
        ((float*)&obs_t[k])[r] = x[(b * (Nn + 1) + n0 + r) * OBSD + k];
    }
    __syncthreads();

    // Layer 1 (K=40): thread t owns column t, explicit 8-deep prefetch.
    {
        float bias1 = be1[t];
        float a1[R] = {bias1, bias1, bias1, bias1};
        float wbuf[8];
#pragma unroll
        for (int p = 0; p < 8; ++p) wbuf[p] = We1[p * Td + t];
#pragma unroll
        for (int k = 0; k < OBSD; ++k) {
            float w = wbuf[k & 7];
            if (k + 8 < OBSD) wbuf[k & 7] = We1[(k + 8) * Td + t];
            float4 ov = obs_t[k];
            a1[0] = fmaf(ov.x, w, a1[0]);
            a1[1] = fmaf(ov.y, w, a1[1]);
            a1[2] = fmaf(ov.z, w, a1[2]);
            a1[3] = fmaf(ov.w, w, a1[3]);
        }
        h1_t[t] = make_float4(fmaxf(a1[0], 0.f), fmaxf(a1[1], 0.f),
                              fmaxf(a1[2], 0.f), fmaxf(a1[3], 0.f));
    }
    __syncthreads();

    // Layer 2: wave wv handles k in [64wv, +64); rotating 8-deep prefetch.
    int wv = t >> 6, c = t & 63;
    {
        float4 a2[R] = {};
        float4 buf[8];
#pragma unroll
        for (int p = 0; p < 8; ++p)
            buf[p] = *(const float4*)(We2 + ((wv << 6) + p) * Td + 4 * c);
#pragma unroll
        for (int i = 0; i < 64; ++i) {
            int k = (wv << 6) + i;
            float4 wvv = buf[i & 7];
            if (i + 8 < 64)
                buf[i & 7] = *(const float4*)(We2 + (k + 8) * Td + 4 * c);
            float4 hv = h1_t[k];
            FMA4(a2[0], hv.x, wvv);
            FMA4(a2[1], hv.y, wvv);
            FMA4(a2[2], hv.z, wvv);
            FMA4(a2[3], hv.w, wvv);
        }
#pragma unroll
        for (int r = 0; r < R; ++r) part[wv][r][c] = a2[r];
    }
    __syncthreads();

    int c2 = t >> 2, j = t & 3;
#pragma unroll
    for (int r = 0; r < R; ++r) {
        float v = be2[t];
#pragma unroll
        for (int w2 = 0; w2 < 4; ++w2) v += ((const float*)&part[w2][r][c2])[j];
        emb[(row0 + r) * Td + t] = fmaxf(v, 0.f);
    }
}

// K2: fused ne + Wn/Wh column-sum, R=4 m-rows per block, grid (64, B),
// plus fence-free last-block-per-batch finalizer (softmax head).
__global__ __launch_bounds__(256, 1) void k_fused(
                        const float* __restrict__ x,
                        const float* __restrict__ adj, const float* __restrict__ emb,
                        const float* __restrict__ Wn, const float* __restrict__ bn,
                        const float* __restrict__ Wh, const float* __restrict__ bh,
                        const float* __restrict__ Wl, const float* __restrict__ bl,
                        const float* __restrict__ Wa, const float* __restrict__ ba,
                        float* __restrict__ snh, float* __restrict__ shid,
                        unsigned* __restrict__ ctr, float* __restrict__ out) {
    int g = blockIdx.x, b = blockIdx.y;
    int t = threadIdx.x;
    int m0 = g * R;
    __shared__ float4 arow_t[Nn];
    __shared__ float4 nrow_t[Td];
    __shared__ float4 partN[4][R][64];
    __shared__ float4 partH[4][R][64];
    arow_t[t] = make_float4(adj[(m0 + 0) * Nn + t], adj[(m0 + 1) * Nn + t],
                            adj[(m0 + 2) * Nn + t], adj[(m0 + 3) * Nn + t]);
    __syncthreads();

    int wv = t >> 6, c = t & 63;
    int c2 = t >> 2, j = t & 3;
    const float* eb = emb + b * Nn * Td;

    // Phase 1: ne, rotating 8-deep prefetch of emb rows.
    {
        float4 aN[R] = {};
        float4 buf[8];
#pragma unroll
        for (int p = 0; p < 8; ++p)
            buf[p] = *(const float4*)(eb + ((wv << 6) + p) * Td + 4 * c);
#pragma unroll
        for (int i = 0; i < 64; ++i) {
            int n = (wv << 6) + i;
            float4 ev = buf[i & 7];
            if (i + 8 < 64)
                buf[i & 7] = *(const float4*)(eb + (n + 8) * Td + 4 * c);
            float4 ar = arow_t[n];
            FMA4(aN[0], ar.x, ev);
            FMA4(aN[1], ar.y, ev);
            FMA4(aN[2], ar.z, ev);
            FMA4(aN[3], ar.w, ev);
        }
#pragma unroll
        for (int r = 0; r < R; ++r) partN[wv][r][c] = aN[r];
    }
    __syncthreads();
    {
        float nr[R];
#pragma unroll
        for (int r = 0; r < R; ++r) {
            float v = 0.f;
#pragma unroll
            for (int w2 = 0; w2 < 4; ++w2) v += ((const float*)&partN[w2][r][c2])[j];
            nr[r] = v;
        }
        nrow_t[t] = make_float4(nr[0], nr[1], nr[2], nr[3]);
    }
    __syncthreads();

    // Phase 2: Wn/Wh dual stream, rotating 4+4 prefetch.
    {
        float4 sN[R] = {};
        float4 sH[R] = {};
        float4 bufN[4], bufH[4];
#pragma unroll
        for (int p = 0; p < 4; ++p) {
            int k = (wv << 6) + p;
            bufN[p] = *(const float4*)(Wn + k * Td + 4 * c);
            bufH[p] = *(const float4*)(Wh + k * Td + 4 * c);
        }
#pragma unroll
        for (int i = 0; i < 64; ++i) {
            int k = (wv << 6) + i;
            float4 wn4 = bufN[i & 3];
            float4 wh4 = bufH[i & 3];
            if (i + 4 < 64) {
                bufN[i & 3] = *(const float4*)(Wn + (k + 4) * Td + 4 * c);
                bufH[i & 3] = *(const float4*)(Wh + (k + 4) * Td + 4 * c);
            }
            float4 nv = nrow_t[k];
            FMA4(sN[0], nv.x, wn4);  FMA4(sH[0], nv.x, wh4);
            FMA4(sN[1], nv.y, wn4);  FMA4(sH[1], nv.y, wh4);
            FMA4(sN[2], nv.z, wn4);  FMA4(sH[2], nv.z, wh4);
            FMA4(sN[3], nv.w, wn4);  FMA4(sH[3], nv.w, wh4);
        }
#pragma unroll
        for (int r = 0; r < R; ++r) { partN[wv][r][c] = sN[r]; partH[wv][r][c] = sH[r]; }
    }
    __syncthreads();

    // Reduce over waves (pre-relu), bias, relu, sum rows, one atomic per col.
    {
        float bnt = bn[t], bht = bh[t];
        float rs1 = 0.f, rs2 = 0.f;
#pragma unroll
        for (int r = 0; r < R; ++r) {
            float v1 = bnt, v2 = bht;
#pragma unroll
            for (int w2 = 0; w2 < 4; ++w2) {
                v1 += ((const float*)&partN[w2][r][c2])[j];
                v2 += ((const float*)&partH[w2][r][c2])[j];
            }
            rs1 += fmaxf(v1, 0.f);
            rs2 += fmaxf(v2, 0.f);
        }
        atomicAdd(&snh[b * Td + t], rs1);
        atomicAdd(&shid[b * Td + t], rs2);
    }

    // --- fence-free last-block-per-batch finalizer ---
    // __syncthreads() drains vmcnt (compiler emits s_waitcnt vmcnt(0) before
    // s_barrier), so our atomics are complete before the ctr bump. No fences.
    __shared__ int isLast;
    __syncthreads();
    if (t == 0) {
        unsigned old = __hip_atomic_fetch_add(&ctr[b], 1u, __ATOMIC_RELAXED,
                                              __HIP_MEMORY_SCOPE_AGENT);
        isLast = (old == (unsigned)(Nn / R - 1));
    }
    __syncthreads();
    if (!isLast) return;

    // Finalizer for batch b. snh/shid read via agent-scope atomic loads
    // (bypass potentially-stale L1/L2); emb/x/weights via plain loads.
    float* erow = (float*)arow_t;          // reuse LDS
    float* lg   = (float*)nrow_t;
    float* p    = (float*)nrow_t + Td;
    float* od   = (float*)nrow_t + 2 * Td;
    int tgt = (int)x[(b * (Nn + 1) + Nn) * OBSD + 0];
    tgt = tgt < 0 ? 0 : (tgt > Nn - 1 ? Nn - 1 : tgt);
    erow[t] = emb[(b * Nn + tgt) * Td + t];
    __syncthreads();

    {
        float4 aL = {};
        float4 buf[8];
#pragma unroll
        for (int pp = 0; pp < 8; ++pp)
            buf[pp] = *(const float4*)(Wl + ((wv << 6) + pp) * Td + 4 * c);
#pragma unroll
        for (int i = 0; i < 64; ++i) {
            int k = (wv << 6) + i;
            float4 wlv = buf[i & 7];
            if (i + 8 < 64)
                buf[i & 7] = *(const float4*)(Wl + (k + 8) * Td + 4 * c);
            FMA4(aL, erow[k], wlv);
        }
        partN[wv][0][c] = aL;
    }
    __syncthreads();

    float acc = bl[t];
#pragma unroll
    for (int w2 = 0; w2 < 4; ++w2) acc += ((const float*)&partN[w2][0][c2])[j];
    float snh_t  = __hip_atomic_load(&snh[b * Td + t],  __ATOMIC_RELAXED,
                                     __HIP_MEMORY_SCOPE_AGENT);
    float shid_t = __hip_atomic_load(&shid[b * Td + t], __ATOMIC_RELAXED,
                                     __HIP_MEMORY_SCOPE_AGENT);
    lg[t] = fmaxf(acc, 0.f) * snh_t;
    __syncthreads();
    int h = t & 7;
    float mx = -1e30f;
#pragma unroll
    for (int d = 0; d < DIMD; ++d) mx = fmaxf(mx, lg[d * HEADS + h]);
    float se = 0.f;
#pragma unroll
    for (int d = 0; d < DIMD; ++d) se += __expf(lg[d * HEADS + h] - mx);
    p[t] = (__expf(lg[t] - mx) / se) * shid_t;
    __syncthreads();
    if (t < DIMD) {
        float s = 0.f;
#pragma unroll
        for (int hh = 0; hh < HEADS; ++hh) s += p[t * HEADS + hh];
        od[t] = s * (1.f / HEADS);
    }
    __syncthreads();
    if (t < ACTD) {
        float s = ba[t];
#pragma unroll
        for (int d = 0; d < DIMD; ++d) s = fmaf(od[d], Wa[d * ACTD + t], s);
        out[b * ACTD + t] = s;
    }
}

extern "C" void kernel_launch(void* const* d_in, const int* in_sizes, int n_in,
                              void* d_out, int out_size, void* d_ws, size_t ws_size,
                              hipStream_t stream) {
    const float* x   = (const float*)d_in[0];
    const float* adj = (const float*)d_in[1];
    const float* We1 = (const float*)d_in[2];
    const float* be1 = (const float*)d_in[3];
    const float* We2 = (const float*)d_in[4];
    const float* be2 = (const float*)d_in[5];
    const float* Wl  = (const float*)d_in[6];
    const float* bl  = (const float*)d_in[7];
    const float* Wn  = (const float*)d_in[8];
    const float* bn  = (const float*)d_in[9];
    const float* Wh  = (const float*)d_in[10];
    const float* bh  = (const float*)d_in[11];
    const float* Wa  = (const float*)d_in[12];
    const float* ba  = (const float*)d_in[13];
    float* out = (float*)d_out;

    // ws layout: emb f32[B*N*T] (1 MB) | snh f32[B*T] | shid f32[B*T] | ctr u32[B]
    float* emb  = (float*)d_ws;
    float* snh  = emb + Bsz * Nn * Td;
    float* shid = snh + Bsz * Td;
    unsigned* ctr = (unsigned*)(shid + Bsz * Td);

    k_emb<<<dim3(Bsz * Nn / R), dim3(Td), 0, stream>>>(x, We1, be1, We2, be2,
                                                       emb, snh, shid, ctr);
    k_fused<<<dim3(Nn / R, Bsz), dim3(Td), 0, stream>>>(x, adj, emb, Wn, bn, Wh, bh,
                                                        Wl, bl, Wa, ba,
                                                        snh, shid, ctr, out);
}

// Round 11
// 100.748 us; speedup vs baseline: 1.0373x; 1.0373x over previous
//
#include <hip/hip_runtime.h>

#define Bsz 4
#define Nn  256
#define OBSD 40
#define ACTD 8
#define HEADS 8
#define DIMD 32
#define Td  256
#define R   4   // rows per block

#define FMA4(accr, s, wv) \
    (accr).x = fmaf((s), (wv).x, (accr).x); \
    (accr).y = fmaf((s), (wv).y, (accr).y); \
    (accr).z = fmaf((s), (wv).z, (accr).z); \
    (accr).w = fmaf((s), (wv).w, (accr).w)

// K1: emb = relu(relu(obs @ We1 + be1) @ We2 + be2), R=4 rows per block.
// grid = 256 blocks x 512 threads (2 waves/SIMD). Blocks 0/1 zero snh/shid.
__global__ __launch_bounds__(512, 1) void k_emb(
                      const float* __restrict__ x,
                      const float* __restrict__ We1, const float* __restrict__ be1,
                      const float* __restrict__ We2, const float* __restrict__ be2,
                      float* __restrict__ emb,
                      float* __restrict__ snh, float* __restrict__ shid) {
    int g = blockIdx.x;
    int t = threadIdx.x;                 // 0..511
    int row0 = g * R;
    int b = row0 >> 8;
    int n0 = row0 & 255;
    if (g == 0)      { for (int i = t; i < Bsz * Td; i += 512) snh[i]  = 0.f; }
    else if (g == 1) { for (int i = t; i < Bsz * Td; i += 512) shid[i] = 0.f; }

    __shared__ float4 obs_t[OBSD];       // 4 rows per obs-channel
    __shared__ float4 h1_t[Td];          // 4 rows per hidden channel
    __shared__ float4 part[8][R][64];    // [wave][row][colgroup] partials (32 KB)
    if (t < R * OBSD) {
        int r = t & (R - 1), k = t >> 2;
        ((float*)&obs_t[k])[r] = x[(b * (Nn + 1) + n0 + r) * OBSD + k];
    }
    __syncthreads();

    // Layer 1 (K=40): threads 0..255 own one column each, 8-deep prefetch.
    if (t < Td) {
        float bias1 = be1[t];
        float a1[R] = {bias1, bias1, bias1, bias1};
        float wbuf[8];
#pragma unroll
        for (int p = 0; p < 8; ++p) wbuf[p] = We1[p * Td + t];
#pragma unroll
        for (int k = 0; k < OBSD; ++k) {
            float w = wbuf[k & 7];
            if (k + 8 < OBSD) wbuf[k & 7] = We1[(k + 8) * Td + t];
            float4 ov = obs_t[k];
            a1[0] = fmaf(ov.x, w, a1[0]);
            a1[1] = fmaf(ov.y, w, a1[1]);
            a1[2] = fmaf(ov.z, w, a1[2]);
            a1[3] = fmaf(ov.w, w, a1[3]);
        }
        h1_t[t] = make_float4(fmaxf(a1[0], 0.f), fmaxf(a1[1], 0.f),
                              fmaxf(a1[2], 0.f), fmaxf(a1[3], 0.f));
    }
    __syncthreads();

    // Layer 2: wave wv (0..7) handles k in [32wv, +32); lane c owns cols 4c..4c+3.
    int wv = t >> 6, c = t & 63;
    {
        float4 a2[R] = {};
        float4 buf[8];
#pragma unroll
        for (int p = 0; p < 8; ++p)
            buf[p] = *(const float4*)(We2 + ((wv << 5) + p) * Td + 4 * c);
#pragma unroll
        for (int i = 0; i < 32; ++i) {
            int k = (wv << 5) + i;
            float4 wvv = buf[i & 7];
            if (i + 8 < 32)
                buf[i & 7] = *(const float4*)(We2 + (k + 8) * Td + 4 * c);
            float4 hv = h1_t[k];
            FMA4(a2[0], hv.x, wvv);
            FMA4(a2[1], hv.y, wvv);
            FMA4(a2[2], hv.z, wvv);
            FMA4(a2[3], hv.w, wvv);
        }
#pragma unroll
        for (int r = 0; r < R; ++r) part[wv][r][c] = a2[r];
    }
    __syncthreads();

    if (t < Td) {
        int c2 = t >> 2, j = t & 3;
#pragma unroll
        for (int r = 0; r < R; ++r) {
            float v = be2[t];
#pragma unroll
            for (int w2 = 0; w2 < 8; ++w2) v += ((const float*)&part[w2][r][c2])[j];
            emb[(row0 + r) * Td + t] = fmaxf(v, 0.f);
        }
    }
}

// K2: fused ne + Wn/Wh column-sum, R=4 m-rows per block.
// grid = (N/R, B) = (64, 4) = 256 blocks x 512 threads (2 waves/SIMD).
__global__ __launch_bounds__(512, 1) void k_fused(
                        const float* __restrict__ adj, const float* __restrict__ emb,
                        const float* __restrict__ Wn, const float* __restrict__ bn,
                        const float* __restrict__ Wh, const float* __restrict__ bh,
                        float* __restrict__ snh, float* __restrict__ shid) {
    int g = blockIdx.x, b = blockIdx.y;
    int t = threadIdx.x;                 // 0..511
    int m0 = g * R;
    __shared__ float4 arow_t[Nn];        // 4 KB
    __shared__ float4 nrow_t[Td];        // 4 KB
    __shared__ float4 partN[8][R][64];   // 32 KB
    __shared__ float4 partH[8][R][64];   // 32 KB
    if (t < Td)
        arow_t[t] = make_float4(adj[(m0 + 0) * Nn + t], adj[(m0 + 1) * Nn + t],
                                adj[(m0 + 2) * Nn + t], adj[(m0 + 3) * Nn + t]);
    __syncthreads();

    int wv = t >> 6, c = t & 63;
    const float* eb = emb + b * Nn * Td;

    // Phase 1: ne. Wave wv sums n in [32wv, +32); 8-deep prefetch.
    {
        float4 aN[R] = {};
        float4 buf[8];
#pragma unroll
        for (int p = 0; p < 8; ++p)
            buf[p] = *(const float4*)(eb + ((wv << 5) + p) * Td + 4 * c);
#pragma unroll
        for (int i = 0; i < 32; ++i) {
            int n = (wv << 5) + i;
            float4 ev = buf[i & 7];
            if (i + 8 < 32)
                buf[i & 7] = *(const float4*)(eb + (n + 8) * Td + 4 * c);
            float4 ar = arow_t[n];
            FMA4(aN[0], ar.x, ev);
            FMA4(aN[1], ar.y, ev);
            FMA4(aN[2], ar.z, ev);
            FMA4(aN[3], ar.w, ev);
        }
#pragma unroll
        for (int r = 0; r < R; ++r) partN[wv][r][c] = aN[r];
    }
    __syncthreads();
    if (t < Td) {
        int c2 = t >> 2, j = t & 3;
        float nr[R];
#pragma unroll
        for (int r = 0; r < R; ++r) {
            float v = 0.f;
#pragma unroll
            for (int w2 = 0; w2 < 8; ++w2) v += ((const float*)&partN[w2][r][c2])[j];
            nr[r] = v;
        }
        nrow_t[t] = make_float4(nr[0], nr[1], nr[2], nr[3]);
    }
    __syncthreads();

    // Phase 2: Wn/Wh dual stream; wave wv handles k in [32wv, +32); 4+4 prefetch.
    {
        float4 sN[R] = {};
        float4 sH[R] = {};
        float4 bufN[4], bufH[4];
#pragma unroll
        for (int p = 0; p < 4; ++p) {
            int k = (wv << 5) + p;
            bufN[p] = *(const float4*)(Wn + k * Td + 4 * c);
            bufH[p] = *(const float4*)(Wh + k * Td + 4 * c);
        }
#pragma unroll
        for (int i = 0; i < 32; ++i) {
            int k = (wv << 5) + i;
            float4 wn4 = bufN[i & 3];
            float4 wh4 = bufH[i & 3];
            if (i + 4 < 32) {
                bufN[i & 3] = *(const float4*)(Wn + (k + 4) * Td + 4 * c);
                bufH[i & 3] = *(const float4*)(Wh + (k + 4) * Td + 4 * c);
            }
            float4 nv = nrow_t[k];
            FMA4(sN[0], nv.x, wn4);  FMA4(sH[0], nv.x, wh4);
            FMA4(sN[1], nv.y, wn4);  FMA4(sH[1], nv.y, wh4);
            FMA4(sN[2], nv.z, wn4);  FMA4(sH[2], nv.z, wh4);
            FMA4(sN[3], nv.w, wn4);  FMA4(sH[3], nv.w, wh4);
        }
#pragma unroll
        for (int r = 0; r < R; ++r) { partN[wv][r][c] = sN[r]; partH[wv][r][c] = sH[r]; }
    }
    __syncthreads();

    // Reduce over 8 waves (pre-relu), bias, relu, sum rows, one atomic per col.
    if (t < Td) {
        int c2 = t >> 2, j = t & 3;
        float bnt = bn[t], bht = bh[t];
        float rs1 = 0.f, rs2 = 0.f;
#pragma unroll
        for (int r = 0; r < R; ++r) {
            float v1 = bnt, v2 = bht;
#pragma unroll
            for (int w2 = 0; w2 < 8; ++w2) {
                v1 += ((const float*)&partN[w2][r][c2])[j];
                v2 += ((const float*)&partH[w2][r][c2])[j];
            }
            rs1 += fmaxf(v1, 0.f);
            rs2 += fmaxf(v2, 0.f);
        }
        atomicAdd(&snh[b * Td + t], rs1);
        atomicAdd(&shid[b * Td + t], rs2);
    }
}

// K3: per-batch target row -> ah -> softmax over DIM per head -> mean -> Wa
__global__ __launch_bounds__(256, 1) void k_final(
                        const float* __restrict__ x, const float* __restrict__ emb,
                        const float* __restrict__ Wl, const float* __restrict__ bl,
                        const float* __restrict__ snh, const float* __restrict__ shid,
                        const float* __restrict__ Wa, const float* __restrict__ ba,
                        float* __restrict__ out) {
    int b = blockIdx.x;
    int t = threadIdx.x;
    int tgt = (int)x[(b * (Nn + 1) + Nn) * OBSD + 0];
    tgt = tgt < 0 ? 0 : (tgt > Nn - 1 ? Nn - 1 : tgt);
    __shared__ float erow[Td], lg[Td], p[Td], od[DIMD];
    __shared__ float4 partL[4][64];
    erow[t] = emb[(b * Nn + tgt) * Td + t];
    __syncthreads();

    int wv = t >> 6, c = t & 63;
    {
        float4 aL = {};
        float4 buf[8];
#pragma unroll
        for (int pp = 0; pp < 8; ++pp)
            buf[pp] = *(const float4*)(Wl + ((wv << 6) + pp) * Td + 4 * c);
#pragma unroll
        for (int i = 0; i < 64; ++i) {
            int k = (wv << 6) + i;
            float4 wlv = buf[i & 7];
            if (i + 8 < 64)
                buf[i & 7] = *(const float4*)(Wl + (k + 8) * Td + 4 * c);
            FMA4(aL, erow[k], wlv);
        }
        partL[wv][c] = aL;
    }
    __syncthreads();

    int c2 = t >> 2, j = t & 3;
    float acc = bl[t];
#pragma unroll
    for (int w2 = 0; w2 < 4; ++w2) acc += ((const float*)&partL[w2][c2])[j];
    float ah = fmaxf(acc, 0.f);
    lg[t] = ah * snh[b * Td + t];
    __syncthreads();
    int h = t & 7;
    float mx = -1e30f;
#pragma unroll
    for (int d = 0; d < DIMD; ++d) mx = fmaxf(mx, lg[d * HEADS + h]);
    float se = 0.f;
#pragma unroll
    for (int d = 0; d < DIMD; ++d) se += __expf(lg[d * HEADS + h] - mx);
    float attn = __expf(lg[t] - mx) / se;
    p[t] = attn * shid[b * Td + t];
    __syncthreads();
    if (t < DIMD) {
        float s = 0.f;
#pragma unroll
        for (int hh = 0; hh < HEADS; ++hh) s += p[t * HEADS + hh];
        od[t] = s * (1.f / HEADS);
    }
    __syncthreads();
    if (t < ACTD) {
        float s = ba[t];
#pragma unroll
        for (int d = 0; d < DIMD; ++d) s = fmaf(od[d], Wa[d * ACTD + t], s);
        out[b * ACTD + t] = s;
    }
}

extern "C" void kernel_launch(void* const* d_in, const int* in_sizes, int n_in,
                              void* d_out, int out_size, void* d_ws, size_t ws_size,
                              hipStream_t stream) {
    const float* x   = (const float*)d_in[0];
    const float* adj = (const float*)d_in[1];
    const float* We1 = (const float*)d_in[2];
    const float* be1 = (const float*)d_in[3];
    const float* We2 = (const float*)d_in[4];
    const float* be2 = (const float*)d_in[5];
    const float* Wl  = (const float*)d_in[6];
    const float* bl  = (const float*)d_in[7];
    const float* Wn  = (const float*)d_in[8];
    const float* bn  = (const float*)d_in[9];
    const float* Wh  = (const float*)d_in[10];
    const float* bh  = (const float*)d_in[11];
    const float* Wa  = (const float*)d_in[12];
    const float* ba  = (const float*)d_in[13];
    float* out = (float*)d_out;

    // ws layout: emb f32[B*N*T] (1 MB) | snh f32[B*T] | shid f32[B*T]
    float* emb  = (float*)d_ws;
    float* snh  = emb + Bsz * Nn * Td;
    float* shid = snh + Bsz * Td;

    k_emb<<<dim3(Bsz * Nn / R), dim3(512), 0, stream>>>(x, We1, be1, We2, be2,
                                                        emb, snh, shid);
    k_fused<<<dim3(Nn / R, Bsz), dim3(512), 0, stream>>>(adj, emb, Wn, bn, Wh, bh,
                                                         snh, shid);
    k_final<<<dim3(Bsz), dim3(256), 0, stream>>>(x, emb, Wl, bl, snh, shid, Wa, ba, out);
}